// Round 1
// baseline (923.493 us; speedup 1.0000x reference)
//
#include <hip/hip_runtime.h>
#include <hip/hip_bf16.h>

#define BLK 256
static constexpr float EPS = 1e-5f;

// z = h * norm  (vectorized float4 over N*64 elements)
__global__ void k_z(const float* __restrict__ hbuf, const float* __restrict__ norm,
                    float4* __restrict__ z, int n16) {
  int i = blockIdx.x * BLK + threadIdx.x;
  if (i >= n16) return;
  float s = norm[i >> 4];
  const float4 v = reinterpret_cast<const float4*>(hbuf)[i];
  z[i] = make_float4(v.x * s, v.y * s, v.z * s, v.w * s);
}

// scores[e] = relu(dot(z[src], z[dst])); atomicMax m[dst] (uint-bitwise, valid for >=0 floats)
__global__ void k_scores(const float4* __restrict__ z, const int* __restrict__ src,
                         const int* __restrict__ dst, float* __restrict__ scores,
                         unsigned int* __restrict__ m, int nE) {
  int t = blockIdx.x * BLK + threadIdx.x;
  int e = t >> 4, sub = t & 15;            // 16 lanes per edge, float4 each -> 64 floats
  if (e >= nE) return;
  int s = src[e], d = dst[e];
  float4 a = z[(size_t)s * 16 + sub];
  float4 b = z[(size_t)d * 16 + sub];
  float p = a.x * b.x + a.y * b.y + a.z * b.z + a.w * b.w;
  p += __shfl_xor(p, 1);
  p += __shfl_xor(p, 2);
  p += __shfl_xor(p, 4);
  p += __shfl_xor(p, 8);
  if (sub == 0) {
    float sc = fmaxf(p, 0.0f);
    scores[e] = sc;
    atomicMax(&m[d], __float_as_uint(sc));  // sc >= 0, m init 0 -> bit order == numeric order
  }
}

// ex = exp(score - m[dst]) (in place); denom[dst] += ex
__global__ void k_ex(float* __restrict__ scores, const float* __restrict__ m,
                     const int* __restrict__ dst, float* __restrict__ denom, int nE) {
  int e = blockIdx.x * BLK + threadIdx.x;
  if (e >= nE) return;
  int d = dst[e];
  float v = expf(scores[e] - m[d]);
  scores[e] = v;
  unsafeAtomicAdd(&denom[d], v);
}

// agg[dst] += (ex/denom[dst]) * z[src]
__global__ void k_agg(const float4* __restrict__ z, const int* __restrict__ src,
                      const int* __restrict__ dst, const float* __restrict__ ex,
                      const float* __restrict__ denom, float* __restrict__ agg, int nE) {
  int t = blockIdx.x * BLK + threadIdx.x;
  int e = t >> 4, sub = t & 15;
  if (e >= nE) return;
  int s = src[e], d = dst[e];
  float w = ex[e] / denom[d];
  float4 a = z[(size_t)s * 16 + sub];
  float* o = agg + (size_t)d * 64 + sub * 4;
  unsafeAtomicAdd(o + 0, a.x * w);
  unsafeAtomicAdd(o + 1, a.y * w);
  unsafeAtomicAdd(o + 2, a.z * w);
  unsafeAtomicAdd(o + 3, a.w * w);
}

// per-column sum / sumsq over N rows (256 rows per block, 4 row-threads per column)
__global__ void k_stats(const float* __restrict__ agg, float* __restrict__ sum,
                        float* __restrict__ sumsq, int n) {
  int col = threadIdx.x & 63;
  int rq  = threadIdx.x >> 6;
  int rend = min(n, (int)(blockIdx.x + 1) * 256);
  float s = 0.f, s2 = 0.f;
  for (int r = blockIdx.x * 256 + rq; r < rend; r += 4) {
    float v = agg[(size_t)r * 64 + col];
    s += v; s2 += v * v;
  }
  unsafeAtomicAdd(&sum[col], s);
  unsafeAtomicAdd(&sumsq[col], s2);
}

__global__ void k_finalize(const float* __restrict__ sum, const float* __restrict__ sumsq,
                           float* __restrict__ mean, float* __restrict__ invstd, float invN) {
  int d = threadIdx.x;
  if (d < 64) {
    float mu = sum[d] * invN;
    mean[d] = mu;
    invstd[d] = rsqrtf(sumsq[d] * invN - mu * mu + EPS);  // biased var, matches jnp.var
  }
}

// h_out[n, head*64+d] = relu(gamma*xhat + beta) * norm[n]
__global__ void k_out(const float* __restrict__ agg, const float* __restrict__ mean,
                      const float* __restrict__ invstd, const float* __restrict__ gamma,
                      const float* __restrict__ beta, const float* __restrict__ norm,
                      float4* __restrict__ out, int n64) {
  int g = blockIdx.x * BLK + threadIdx.x;   // float4 index over N * 64 (= N*256 floats)
  if (g >= n64) return;
  int node = g >> 6, within = g & 63;
  int head = within >> 4, d4 = within & 15;
  float4 a  = reinterpret_cast<const float4*>(agg)[(size_t)node * 16 + d4];
  float4 mu = reinterpret_cast<const float4*>(mean)[d4];
  float4 iv = reinterpret_cast<const float4*>(invstd)[d4];
  float4 ga = reinterpret_cast<const float4*>(gamma)[head * 16 + d4];
  float4 be = reinterpret_cast<const float4*>(beta)[head * 16 + d4];
  float s = norm[node];
  float4 r;
  r.x = fmaxf(fmaf(ga.x, (a.x - mu.x) * iv.x, be.x), 0.f) * s;
  r.y = fmaxf(fmaf(ga.y, (a.y - mu.y) * iv.y, be.y), 0.f) * s;
  r.z = fmaxf(fmaf(ga.z, (a.z - mu.z) * iv.z, be.z), 0.f) * s;
  r.w = fmaxf(fmaf(ga.w, (a.w - mu.w) * iv.w, be.w), 0.f) * s;
  out[g] = r;
}

extern "C" void kernel_launch(void* const* d_in, const int* in_sizes, int n_in,
                              void* d_out, int out_size, void* d_ws, size_t ws_size,
                              hipStream_t stream) {
  const float* h     = (const float*)d_in[0];
  const float* e     = (const float*)d_in[1];
  const float* norm  = (const float*)d_in[2];
  const float* gamma = (const float*)d_in[3];
  const float* beta  = (const float*)d_in[4];
  const int*   src   = (const int*)d_in[5];
  const int*   dst   = (const int*)d_in[6];
  const int N = in_sizes[2];   // norm has N elements
  const int E = in_sizes[5];   // src has E elements
  float* out = (float*)d_out;

  // Scratch lives in the e-passthrough region of d_out (204.8 MB >> 29.3 MB needed).
  // All compute kernels finish before the final d2d copy overwrites it.
  char* scratch = (char*)(out + (size_t)N * 256);
  size_t offZ      = 0;
  size_t offScores = offZ + (size_t)N * 64 * sizeof(float);
  size_t offAgg    = offScores + (size_t)E * sizeof(float);
  size_t offM      = offAgg + (size_t)N * 64 * sizeof(float);
  size_t offDenom  = offM + (size_t)N * sizeof(float);
  size_t offStats  = offDenom + (size_t)N * sizeof(float);

  float4*       z      = (float4*)(scratch + offZ);
  float*        scores = (float*)(scratch + offScores);   // reused as ex in-place
  float*        agg    = (float*)(scratch + offAgg);
  unsigned int* m      = (unsigned int*)(scratch + offM);
  float*        denom  = (float*)(scratch + offDenom);
  float*        sum    = (float*)(scratch + offStats);
  float*        sumsq  = sum + 64;
  float*        mean   = sumsq + 64;
  float*        invstd = mean + 64;

  // zero agg + m + denom + sum/sumsq (mean/invstd are fully written)
  hipMemsetAsync(scratch + offAgg, 0, (offStats + 4 * 64 * sizeof(float)) - offAgg, stream);

  int n16 = N * 16;
  k_z<<<(n16 + BLK - 1) / BLK, BLK, 0, stream>>>(h, norm, z, n16);

  int et = E * 16;
  k_scores<<<(et + BLK - 1) / BLK, BLK, 0, stream>>>(z, src, dst, scores, m, E);
  k_ex<<<(E + BLK - 1) / BLK, BLK, 0, stream>>>(scores, (const float*)m, dst, denom, E);
  k_agg<<<(et + BLK - 1) / BLK, BLK, 0, stream>>>(z, src, dst, scores, denom, agg, E);

  k_stats<<<(N + 255) / 256, 256, 0, stream>>>(agg, sum, sumsq, N);
  k_finalize<<<1, 64, 0, stream>>>(sum, sumsq, mean, invstd, 1.0f / (float)N);

  int n64 = N * 64;
  k_out<<<(n64 + BLK - 1) / BLK, BLK, 0, stream>>>(agg, mean, invstd, gamma, beta, norm,
                                                   (float4*)out, n64);

  // e passthrough last — overwrites the scratch region
  hipMemcpyAsync(out + (size_t)N * 256, e, (size_t)E * 64 * sizeof(float),
                 hipMemcpyDeviceToDevice, stream);
}

// Round 2
// 342.014 us; speedup vs baseline: 2.7002x; 2.7002x over previous
//
#include <hip/hip_runtime.h>
#include <hip/hip_bf16.h>

#define BLK 256
static constexpr float EPS = 1e-5f;

// z = h * norm  (vectorized float4 over N*64 elements)
__global__ void k_z(const float* __restrict__ hbuf, const float* __restrict__ norm,
                    float4* __restrict__ z, int n16) {
  int i = blockIdx.x * BLK + threadIdx.x;
  if (i >= n16) return;
  float s = norm[i >> 4];
  const float4 v = reinterpret_cast<const float4*>(hbuf)[i];
  z[i] = make_float4(v.x * s, v.y * s, v.z * s, v.w * s);
}

// scores[e] = relu(dot(z[src], z[dst]))   (16 lanes per edge)
__global__ void k_scores(const float4* __restrict__ z, const int* __restrict__ src,
                         const int* __restrict__ dst, float* __restrict__ scores, int nE) {
  int t = blockIdx.x * BLK + threadIdx.x;
  int e = t >> 4, sub = t & 15;
  if (e >= nE) return;
  int s = src[e], d = dst[e];
  float4 a = z[(size_t)s * 16 + sub];
  float4 b = z[(size_t)d * 16 + sub];
  float p = a.x * b.x + a.y * b.y + a.z * b.z + a.w * b.w;
  p += __shfl_xor(p, 1);
  p += __shfl_xor(p, 2);
  p += __shfl_xor(p, 4);
  p += __shfl_xor(p, 8);
  if (sub == 0) scores[e] = fmaxf(p, 0.0f);
}

// ---- CSR build ----
__global__ void k_count(const int* __restrict__ dst, int* __restrict__ deg, int nE) {
  int e = blockIdx.x * BLK + threadIdx.x;
  if (e < nE) atomicAdd(&deg[dst[e]], 1);
}

// inclusive block scan (1024/block) -> incl, per-block totals -> bsum
__global__ void k_scan1(const int* __restrict__ deg, int* __restrict__ incl,
                        int* __restrict__ bsum, int n) {
  __shared__ int s[1024];
  int t = threadIdx.x;
  int i = blockIdx.x * 1024 + t;
  s[t] = (i < n) ? deg[i] : 0;
  __syncthreads();
  for (int off = 1; off < 1024; off <<= 1) {
    int x = (t >= off) ? s[t - off] : 0;
    __syncthreads();
    s[t] += x;
    __syncthreads();
  }
  if (i < n) incl[i] = s[t];
  if (t == 1023) bsum[blockIdx.x] = s[1023];
}

__global__ void k_scan2(int* __restrict__ bsum, int* __restrict__ bpref, int nb) {
  if (threadIdx.x == 0) {
    int run = 0;
    for (int b = 0; b < nb; ++b) { bpref[b] = run; run += bsum[b]; }
  }
}

__global__ void k_scan3(const int* __restrict__ incl, const int* __restrict__ deg,
                        const int* __restrict__ bpref, int* __restrict__ start,
                        int* __restrict__ cursor, int n) {
  int i = blockIdx.x * BLK + threadIdx.x;
  if (i >= n) return;
  int st = incl[i] - deg[i] + bpref[i >> 10];
  start[i] = st;
  cursor[i] = st;
}

// scatter edges into CSR slots (order within a node nondeterministic; fp-sum
// reassociation only, well under threshold)
__global__ void k_scatter(const int* __restrict__ src, const int* __restrict__ dst,
                          const float* __restrict__ scores, int* __restrict__ cursor,
                          int* __restrict__ csr_src, float* __restrict__ csr_w, int nE) {
  int e = blockIdx.x * BLK + threadIdx.x;
  if (e >= nE) return;
  int d = dst[e];
  int slot = atomicAdd(&cursor[d], 1);
  csr_src[slot] = src[e];
  csr_w[slot] = scores[e];
}

// one wave per dst node: segment max -> exp/denom -> weighted gather-sum, one row write
__global__ void k_nodeagg(const float* __restrict__ z, const int* __restrict__ start,
                          const int* __restrict__ deg, const int* __restrict__ csr_src,
                          const float* __restrict__ csr_w, float* __restrict__ agg, int n) {
  int w = (blockIdx.x * BLK + threadIdx.x) >> 6;
  int lane = threadIdx.x & 63;
  if (w >= n) return;
  int beg = start[w], cnt = deg[w];

  // pass 1: max (scores >= 0; empty segment -> 0, matching reference)
  float m = 0.f;
  for (int i = lane; i < cnt; i += 64) m = fmaxf(m, csr_w[beg + i]);
  #pragma unroll
  for (int off = 1; off < 64; off <<= 1) m = fmaxf(m, __shfl_xor(m, off));

  // pass 2: exp + denom + weighted aggregation (lane = feature dim)
  float acc = 0.f, dsum = 0.f;
  for (int base = 0; base < cnt; base += 64) {
    int idx = base + lane;
    float wv = 0.f; int sv = 0;
    if (idx < cnt) { wv = expf(csr_w[beg + idx] - m); sv = csr_src[beg + idx]; }
    dsum += wv;
    int c = min(64, cnt - base);
    #pragma unroll 4
    for (int j = 0; j < c; ++j) {
      float wj = __shfl(wv, j);
      int   sj = __shfl(sv, j);
      acc = fmaf(wj, z[(size_t)sj * 64 + lane], acc);
    }
  }
  #pragma unroll
  for (int off = 1; off < 64; off <<= 1) dsum += __shfl_xor(dsum, off);
  float inv = (dsum > 0.f) ? 1.0f / dsum : 0.f;
  agg[(size_t)w * 64 + lane] = acc * inv;
}

// per-column sum / sumsq over N rows
__global__ void k_stats(const float* __restrict__ agg, float* __restrict__ sum,
                        float* __restrict__ sumsq, int n) {
  int col = threadIdx.x & 63;
  int rq  = threadIdx.x >> 6;
  int rend = min(n, (int)(blockIdx.x + 1) * 256);
  float s = 0.f, s2 = 0.f;
  for (int r = blockIdx.x * 256 + rq; r < rend; r += 4) {
    float v = agg[(size_t)r * 64 + col];
    s += v; s2 += v * v;
  }
  unsafeAtomicAdd(&sum[col], s);
  unsafeAtomicAdd(&sumsq[col], s2);
}

__global__ void k_finalize(const float* __restrict__ sum, const float* __restrict__ sumsq,
                           float* __restrict__ mean, float* __restrict__ invstd, float invN) {
  int d = threadIdx.x;
  if (d < 64) {
    float mu = sum[d] * invN;
    mean[d] = mu;
    invstd[d] = rsqrtf(sumsq[d] * invN - mu * mu + EPS);
  }
}

// h_out[n, head*64+d] = relu(gamma*xhat + beta) * norm[n]
__global__ void k_out(const float* __restrict__ agg, const float* __restrict__ mean,
                      const float* __restrict__ invstd, const float* __restrict__ gamma,
                      const float* __restrict__ beta, const float* __restrict__ norm,
                      float4* __restrict__ out, int n64) {
  int g = blockIdx.x * BLK + threadIdx.x;
  if (g >= n64) return;
  int node = g >> 6, within = g & 63;
  int head = within >> 4, d4 = within & 15;
  float4 a  = reinterpret_cast<const float4*>(agg)[(size_t)node * 16 + d4];
  float4 mu = reinterpret_cast<const float4*>(mean)[d4];
  float4 iv = reinterpret_cast<const float4*>(invstd)[d4];
  float4 ga = reinterpret_cast<const float4*>(gamma)[head * 16 + d4];
  float4 be = reinterpret_cast<const float4*>(beta)[head * 16 + d4];
  float s = norm[node];
  float4 r;
  r.x = fmaxf(fmaf(ga.x, (a.x - mu.x) * iv.x, be.x), 0.f) * s;
  r.y = fmaxf(fmaf(ga.y, (a.y - mu.y) * iv.y, be.y), 0.f) * s;
  r.z = fmaxf(fmaf(ga.z, (a.z - mu.z) * iv.z, be.z), 0.f) * s;
  r.w = fmaxf(fmaf(ga.w, (a.w - mu.w) * iv.w, be.w), 0.f) * s;
  out[g] = r;
}

extern "C" void kernel_launch(void* const* d_in, const int* in_sizes, int n_in,
                              void* d_out, int out_size, void* d_ws, size_t ws_size,
                              hipStream_t stream) {
  const float* h     = (const float*)d_in[0];
  const float* e     = (const float*)d_in[1];
  const float* norm  = (const float*)d_in[2];
  const float* gamma = (const float*)d_in[3];
  const float* beta  = (const float*)d_in[4];
  const int*   src   = (const int*)d_in[5];
  const int*   dst   = (const int*)d_in[6];
  const int N = in_sizes[2];
  const int E = in_sizes[5];
  float* out = (float*)d_out;

  // Scratch lives in the e-passthrough region of d_out (204.8 MB >> ~37 MB used).
  // All compute kernels finish before the final d2d copy overwrites it.
  char* scratch = (char*)(out + (size_t)N * 256);
  size_t off = 0;
  auto carve = [&](size_t bytes) { void* p = scratch + off; off += (bytes + 255) & ~(size_t)255; return p; };

  float4* z       = (float4*)carve((size_t)N * 64 * sizeof(float));
  float*  scores  = (float*) carve((size_t)E * sizeof(float));
  float*  agg     = (float*) carve((size_t)N * 64 * sizeof(float));
  int*    csr_src = (int*)   carve((size_t)E * sizeof(int));
  float*  csr_w   = (float*) carve((size_t)E * sizeof(float));
  int*    incl    = (int*)   carve((size_t)N * sizeof(int));
  int*    start   = (int*)   carve((size_t)N * sizeof(int));
  int*    cursor  = (int*)   carve((size_t)N * sizeof(int));
  int*    bsum    = (int*)   carve(256 * sizeof(int));
  int*    bpref   = (int*)   carve(256 * sizeof(int));
  char*   zero0   = (char*)  carve(0);                         // start of memset region
  int*    deg     = (int*)   carve((size_t)N * sizeof(int));
  float*  sum     = (float*) carve(64 * sizeof(float));
  float*  sumsq   = (float*) carve(64 * sizeof(float));
  float*  mean    = (float*) carve(64 * sizeof(float));
  float*  invstd  = (float*) carve(64 * sizeof(float));
  size_t  zbytes  = (scratch + off) - zero0;

  hipMemsetAsync(zero0, 0, zbytes, stream);

  int n16 = N * 16;
  k_z<<<(n16 + BLK - 1) / BLK, BLK, 0, stream>>>(h, norm, z, n16);

  int et = E * 16;
  k_scores<<<(et + BLK - 1) / BLK, BLK, 0, stream>>>(z, src, dst, scores, E);

  k_count<<<(E + BLK - 1) / BLK, BLK, 0, stream>>>(dst, deg, E);
  int nb = (N + 1023) / 1024;
  k_scan1<<<nb, 1024, 0, stream>>>(deg, incl, bsum, N);
  k_scan2<<<1, 64, 0, stream>>>(bsum, bpref, nb);
  k_scan3<<<(N + BLK - 1) / BLK, BLK, 0, stream>>>(incl, deg, bpref, start, cursor, N);
  k_scatter<<<(E + BLK - 1) / BLK, BLK, 0, stream>>>(src, dst, scores, cursor, csr_src, csr_w, E);

  int nt = N * 64;  // one wave per node
  k_nodeagg<<<(nt + BLK - 1) / BLK, BLK, 0, stream>>>((const float*)z, start, deg, csr_src, csr_w, agg, N);

  k_stats<<<(N + 255) / 256, 256, 0, stream>>>(agg, sum, sumsq, N);
  k_finalize<<<1, 64, 0, stream>>>(sum, sumsq, mean, invstd, 1.0f / (float)N);

  int n64 = N * 64;
  k_out<<<(n64 + BLK - 1) / BLK, BLK, 0, stream>>>(agg, mean, invstd, gamma, beta, norm,
                                                   (float4*)out, n64);

  hipMemcpyAsync(out + (size_t)N * 256, e, (size_t)E * 64 * sizeof(float),
                 hipMemcpyDeviceToDevice, stream);
}